// Round 1
// baseline (429.077 us; speedup 1.0000x reference)
//
#include <hip/hip_runtime.h>

// Capsule routing, B=32 I=64 J=1152 K=32 M=16, routings=3.
// Strategy: never materialize u_hat (302MB). 5 passes recompute it from W:
//   pass1: s0 = (1/64)*sum_j u_hat          (k_s<FIRST=1>)
//   pass2: b1 = sum_k o0*u_hat              (k_agree<ADD=0>)
//   pass3: s1 = sum_j c1*u_hat              (k_s<0>)
//   pass4: b2 = b1 + sum_k o1*u_hat         (k_agree<1>)
//   pass5: s2 = sum_j c2*u_hat              (k_s<0>)
// plus tiny squash / softmax kernels.

#define Bb 32
#define Ii 64
#define Jj 1152
#define Kk 32
#define Mm 16

#define JC 8       // j's staged at a time
#define NCH 4      // chunks per block -> 32 j per block
#define NJB 36     // J / 32

// LDS layouts (floats):
//  W_lds: [jq=8][k=32] rows, row stride 20 (16 + 4 pad)  -> 8*640 = 5120
//  x_lds: [b=32] blocks of stride 168 (8 jq * 20 + 8 pad) -> 32*168 = 5376
#define WLDS 5120
#define XLDS 5376

__device__ __forceinline__ float dot4(float4 a, float4 b){
  return a.x*b.x + a.y*b.y + a.z*b.z + a.w*b.w;
}

// ---- staging helpers (identical pattern in both pass kernels) -------------
__device__ __forceinline__ void stage_tiles(const float* __restrict__ wbase, int ch,
                                            const float* __restrict__ xp, int jc0,
                                            float* Wl, float* xl, int t)
{
  // W chunk: 8 j * 512 = 4096 floats, global is linear from wbase+ch*4096.
#pragma unroll
  for (int q=0;q<4;q++){
    int f   = (t + q*256)*4;
    int row = f >> 4;              // 0..255 = (jqq,k)
    int k   = row & 31, jqq = row >> 5, m = f & 15;
    float4 v = *reinterpret_cast<const float4*>(wbase + ch*4096 + f);
    *reinterpret_cast<float4*>(&Wl[jqq*640 + k*20 + m]) = v;
  }
  // x chunk: 32 b * 8 j * 16 m = 4096 floats; per-b 128 contiguous floats.
#pragma unroll
  for (int q=0;q<4;q++){
    int f = (t + q*256)*4;
    int b = f >> 7, rem = f & 127;
    int jqq = rem >> 4, m = rem & 15;
    float4 v = *reinterpret_cast<const float4*>(xp + (size_t)b*18432 + jc0*16 + rem);
    *reinterpret_cast<float4*>(&xl[b*168 + jqq*20 + m]) = v;
  }
}

// compute u_hat tile for this thread: 8 b's (bg+4*bb) x 4 k's (kg+8*kk), one j (jq)
__device__ __forceinline__ void compute_uhat(const float* Wl, const float* xl,
                                             int jq, int bg, int kg, float uh[8][4])
{
#pragma unroll
  for (int a=0;a<8;a++)
#pragma unroll
    for (int q=0;q<4;q++) uh[a][q]=0.f;
#pragma unroll
  for (int mq=0; mq<4; ++mq) {
    float4 xr[8];
#pragma unroll
    for (int bb=0;bb<8;bb++)
      xr[bb] = *reinterpret_cast<const float4*>(&xl[(bg + 4*bb)*168 + jq*20 + mq*4]);
#pragma unroll
    for (int kk=0;kk<4;kk++){
      float4 wv = *reinterpret_cast<const float4*>(&Wl[jq*640 + (kg + 8*kk)*20 + mq*4]);
#pragma unroll
      for (int bb=0;bb<8;bb++)
        uh[bb][kk] += dot4(wv, xr[bb]);
    }
  }
}

// ---- s pass: s[b,i,k] += sum_j c[b,i,j] * u_hat[b,i,j,k] ------------------
template<int FIRST>
__global__ __launch_bounds__(256, 2)
void k_s(const float* __restrict__ Wp, const float* __restrict__ xp,
         const float* __restrict__ cp, float* __restrict__ sp)
{
  __shared__ float sm[WLDS + XLDS + 288];   // W | x | c ; reduce buffer aliases front
  float* Wl = sm;
  float* xl = sm + WLDS;
  float* cl = sm + WLDS + XLDS;             // [b] stride 9

  const int t  = threadIdx.x;
  const int jq = t >> 5;
  const int g  = t & 31;
  const int bg = g >> 3;   // 0..3, b = bg + 4*bb
  const int kg = g & 7;    // 0..7, k = kg + 8*kk
  const int i  = blockIdx.y;
  const int j0 = blockIdx.x * (JC*NCH);

  float acc[8][4];
#pragma unroll
  for (int a=0;a<8;a++)
#pragma unroll
    for (int q=0;q<4;q++) acc[a][q]=0.f;

  const float* wbase = Wp + (size_t)i*589824 + (size_t)j0*512;

  for (int ch=0; ch<NCH; ++ch) {
    const int jc0 = j0 + ch*JC;
    __syncthreads();
    stage_tiles(wbase, ch, xp, jc0, Wl, xl, t);
    if (!FIRST && t < 64) {
      int f = t*4; int b = f >> 3; int jj = f & 7;
      float4 v = *reinterpret_cast<const float4*>(cp + ((size_t)b*Ii + i)*Jj + jc0 + jj);
      cl[b*9+jj]   = v.x; cl[b*9+jj+1] = v.y;
      cl[b*9+jj+2] = v.z; cl[b*9+jj+3] = v.w;
    }
    __syncthreads();

    float uh[8][4];
    compute_uhat(Wl, xl, jq, bg, kg, uh);

#pragma unroll
    for (int bb=0;bb<8;bb++){
      float cw = FIRST ? (1.0f/64.0f) : cl[(bg+4*bb)*9 + jq];
#pragma unroll
      for (int kk=0;kk<4;kk++) acc[bb][kk] += cw * uh[bb][kk];
    }
  }

  // reduce partial s over jq (8 threads share each (g, bb, kk)) then atomicAdd
  __syncthreads();
  float* al = sm;            // 8192 floats: [jq][g][bb*4+kk]
#pragma unroll
  for (int bb=0;bb<8;bb++)
#pragma unroll
    for (int kk=0;kk<4;kk++)
      al[jq*1024 + g*32 + bb*4 + kk] = acc[bb][kk];
  __syncthreads();

  float4 v = make_float4(0.f,0.f,0.f,0.f);
#pragma unroll
  for (int q=0;q<8;q++){
    float4 a4 = *reinterpret_cast<float4*>(&al[q*1024 + t*4]);
    v.x += a4.x; v.y += a4.y; v.z += a4.z; v.w += a4.w;
  }
  const int o0  = t*4;
  const int gg  = o0 >> 5;
  const int idx = o0 & 31;
  const int bgx = gg >> 3, kgx = gg & 7;
  float vals[4] = {v.x, v.y, v.z, v.w};
#pragma unroll
  for (int q=0;q<4;q++){
    int ii = idx + q;
    int bb = ii >> 2, kk = ii & 3;
    int b = bgx + 4*bb, k = kgx + 8*kk;
    atomicAdd(&sp[((size_t)b*Ii + i)*Kk + k], vals[q]);
  }
}

// ---- agree pass: br[i,b,j] (+)= sum_k o[b,i,k]*u_hat[b,i,j,k] -------------
template<int ADD>
__global__ __launch_bounds__(256, 2)
void k_agree(const float* __restrict__ Wp, const float* __restrict__ xp,
             const float* __restrict__ op, float* __restrict__ brp)
{
  __shared__ float sm[WLDS + XLDS];
  __shared__ float ar[2048];   // [jq][g][bb]
  __shared__ float bw[1024];   // [b][jrel 0..31]
  float* Wl = sm;
  float* xl = sm + WLDS;

  const int t  = threadIdx.x;
  const int jq = t >> 5;
  const int g  = t & 31;
  const int bg = g >> 3;
  const int kg = g & 7;
  const int i  = blockIdx.y;
  const int j0 = blockIdx.x * (JC*NCH);

  float ot[8][4];
#pragma unroll
  for (int bb=0;bb<8;bb++)
#pragma unroll
    for (int kk=0;kk<4;kk++)
      ot[bb][kk] = op[((size_t)(bg+4*bb)*Ii + i)*Kk + kg + 8*kk];

  const float* wbase = Wp + (size_t)i*589824 + (size_t)j0*512;

  for (int ch=0; ch<NCH; ++ch) {
    const int jc0 = j0 + ch*JC;
    __syncthreads();
    stage_tiles(wbase, ch, xp, jc0, Wl, xl, t);
    __syncthreads();

    float uh[8][4];
    compute_uhat(Wl, xl, jq, bg, kg, uh);

#pragma unroll
    for (int bb=0;bb<8;bb++){
      float ap = 0.f;
#pragma unroll
      for (int kk=0;kk<4;kk++) ap += ot[bb][kk]*uh[bb][kk];
      ar[jq*256 + g*8 + bb] = ap;
    }
    __syncthreads();
    {
      int b_o = t >> 3, jr = t & 7;
      int bgo = b_o & 3, bbo = b_o >> 2;
      float vsum = 0.f;
#pragma unroll
      for (int k2=0;k2<8;k2++)
        vsum += ar[jr*256 + (bgo*8 + k2)*8 + bbo];
      bw[b_o*32 + ch*8 + jr] = vsum;
    }
  }
  __syncthreads();
  {
    int b_o = t >> 3, seg = t & 7;
    float4 v = *reinterpret_cast<float4*>(&bw[b_o*32 + seg*4]);
    size_t gi = (size_t)i*36864 + (size_t)b_o*Jj + j0 + seg*4;
    if (ADD) {
      float4 old = *reinterpret_cast<const float4*>(&brp[gi]);
      v.x += old.x; v.y += old.y; v.z += old.z; v.w += old.w;
    }
    *reinterpret_cast<float4*>(&brp[gi]) = v;
  }
}

// ---- softmax over i: c[b,i,j] = softmax_i(br[i,b,j]) ----------------------
__global__ void k_soft(const float* __restrict__ brp, float* __restrict__ cp)
{
  __shared__ float sm[64*65];
  const int b = blockIdx.y, j0 = blockIdx.x*64, l = threadIdx.x;
#pragma unroll 8
  for (int ii=0; ii<64; ++ii)
    sm[ii*65 + l] = brp[(size_t)ii*36864 + (size_t)b*Jj + j0 + l];
  __syncthreads();
  float mx = -1e30f;
#pragma unroll 8
  for (int ii=0; ii<64; ++ii) mx = fmaxf(mx, sm[ii*65+l]);
  float sum = 0.f;
#pragma unroll 8
  for (int ii=0; ii<64; ++ii){
    float e = __expf(sm[ii*65+l] - mx);
    sm[ii*65+l] = e; sum += e;
  }
  float inv = 1.0f / sum;
#pragma unroll 8
  for (int ii=0; ii<64; ++ii)
    cp[((size_t)b*Ii+ii)*Jj + j0 + l] = sm[ii*65+l]*inv;
}

// ---- squash rows of 32 ----------------------------------------------------
__global__ void k_squash(const float* __restrict__ sp, float* __restrict__ op)
{
  int r = blockIdx.x*blockDim.x + threadIdx.x;
  if (r >= Bb*Ii) return;
  const float* row = sp + (size_t)r*Kk;
  float4 q[8];
  float s2 = 0.f;
#pragma unroll
  for (int u=0;u<8;u++){
    q[u] = *reinterpret_cast<const float4*>(row + u*4);
    s2 += q[u].x*q[u].x + q[u].y*q[u].y + q[u].z*q[u].z + q[u].w*q[u].w;
  }
  float scale = s2/(1.f+s2) * rsqrtf(s2 + 1e-7f);
  float* orow = op + (size_t)r*Kk;
#pragma unroll
  for (int u=0;u<8;u++){
    float4 w = q[u];
    w.x*=scale; w.y*=scale; w.z*=scale; w.w*=scale;
    *reinterpret_cast<float4*>(orow + u*4) = w;
  }
}

extern "C" void kernel_launch(void* const* d_in, const int* in_sizes, int n_in,
                              void* d_out, int out_size, void* d_ws, size_t ws_size,
                              hipStream_t stream)
{
  const float* x  = (const float*)d_in[0];   // [B,J,M]
  const float* Wp = (const float*)d_in[1];   // [I,J,K,M]
  float* out = (float*)d_out;                // [B,I,K] f32
  float* ws  = (float*)d_ws;
  // ws layout (floats): s 65536 | o 65536 | br 2359296 | c 2359296  (~19.4MB)
  float* s  = ws;
  float* o  = ws + 65536;
  float* br = ws + 131072;
  float* c  = ws + 2490368;

  dim3 gs(NJB, Ii), bs(256);
  dim3 gsm(Jj/64, Bb), bsm(64);

  // iter 0: c uniform 1/64
  hipMemsetAsync(s, 0, 65536*sizeof(float), stream);
  k_s<1><<<gs, bs, 0, stream>>>(Wp, x, nullptr, s);
  k_squash<<<dim3(8), dim3(256), 0, stream>>>(s, o);
  k_agree<0><<<gs, bs, 0, stream>>>(Wp, x, o, br);
  k_soft<<<gsm, bsm, 0, stream>>>(br, c);

  // iter 1
  hipMemsetAsync(s, 0, 65536*sizeof(float), stream);
  k_s<0><<<gs, bs, 0, stream>>>(Wp, x, c, s);
  k_squash<<<dim3(8), dim3(256), 0, stream>>>(s, o);
  k_agree<1><<<gs, bs, 0, stream>>>(Wp, x, o, br);
  k_soft<<<gsm, bsm, 0, stream>>>(br, c);

  // iter 2
  hipMemsetAsync(s, 0, 65536*sizeof(float), stream);
  k_s<0><<<gs, bs, 0, stream>>>(Wp, x, c, s);
  k_squash<<<dim3(8), dim3(256), 0, stream>>>(s, out);
}